// Round 4
// baseline (211.984 us; speedup 1.0000x reference)
//
#include <hip/hip_runtime.h>

// Problem constants (match reference)
#define BB 8
#define CC 3
#define HH 1024
#define WW 1024
#define NS 15728   // int(1024*1024*0.015)

// Gaussian 5-tap, sigma=1.5, normalized
#define G0 0.1200784f
#define G1 0.2338808f
#define G2 0.2920816f

// ---------------------------------------------------------------------------
// Kernel 1: scatter snow boxes into a per-batch bitmask (1 bit / pixel).
// mbits layout: [B][H][W/32] uint32 -> 32 words per image row.
// ---------------------------------------------------------------------------
__global__ __launch_bounds__(256) void snow_mask_kernel(
    const int* __restrict__ ys, const int* __restrict__ xs,
    const int* __restrict__ rs, unsigned int* __restrict__ mbits) {
  int s = blockIdx.x * 256 + threadIdx.x;
  if (s >= NS) return;
  int b = blockIdx.y;
  int idx = b * NS + s;
  int y = ys[idx];
  int x = xs[idx];
  int r = rs[idx] + 1;  // radius in {1,2,3}
  int x0 = max(x - r, 0), x1 = min(x + r, WW - 1);
  int y0 = max(y - r, 0), y1 = min(y + r, HH - 1);
  int w0 = x0 >> 5, w1 = x1 >> 5;
  unsigned int m0 = 0xFFFFFFFFu << (x0 & 31);
  unsigned int m1 = 0xFFFFFFFFu >> (31 - (x1 & 31));
  for (int py = y0; py <= y1; ++py) {
    unsigned int* rowp = mbits + ((unsigned)(b * HH + py) << 5);
    if (w0 == w1) {
      atomicOr(&rowp[w0], m0 & m1);
    } else {
      atomicOr(&rowp[w0], m0);
      atomicOr(&rowp[w1], m1);
    }
  }
}

// ---------------------------------------------------------------------------
// Kernel 2: masked-fill (0.95) + separable 5x5 Gaussian + clip, fused.
// Output tile 128x32 per block, 256 threads, one (b,c) per blockIdx.z.
// LDS: raw masked tile 36 rows x 140-float stride (20160 B -> 8 blocks/CU,
//   100% wave occupancy with __launch_bounds__(256,8)).
// Load phase: branch-free clamped coords + OOB zero; 5 independent float4
//   loads per thread (high MLP), predicated LDS store on the tail slot.
// Compute: each thread = 4 cols (float4) x 4 rows; horizontal 5-tap from
//   3 wide LDS reads per row, vertical 5-tap register sliding window.
// ---------------------------------------------------------------------------
#define TS 140           // LDS row stride in floats
#define TR 36            // tile rows (32 output + 4 halo)
#define NLOAD (TR * 34)  // 1224 float4 loads

__global__ __launch_bounds__(256, 8) void snow_blur_kernel(
    const float* __restrict__ x, const unsigned int* __restrict__ mbits,
    float* __restrict__ out) {
  __shared__ float tile[TR * TS];

  const int bz = blockIdx.z;        // b*CC + c
  const int b = bz / CC;
  const int bx = blockIdx.x, by = blockIdx.y;
  const int tid = threadIdx.x;
  const float* __restrict__ xp = x + (size_t)bz * (HH * WW);
  const unsigned int* __restrict__ mb = mbits + ((unsigned)(b * HH) << 5);

  const int gxbase = bx * 128 - 4;  // image col of tile col 0 (16B aligned)
  const int gybase = by * 32 - 2;   // image row of tile row 0

  // ---- load phase: 5 slots/thread, all loads independent ----
  float4 v[5];
  unsigned int bits[5];
  int lidx[5];
#pragma unroll
  for (int k = 0; k < 5; ++k) {
    int i = tid + k * 256;
    i = i < (NLOAD - 1) ? i : (NLOAD - 1);   // clamp, no branch
    int r = i / 34;
    int c4 = i - r * 34;
    int gy = gybase + r;
    int gx = gxbase + c4 * 4;
    int gyc = min(max(gy, 0), HH - 1);
    int gxc = min(max(gx, 0), WW - 4);       // f4 segments fully in or out
    v[k] = *(const float4*)(xp + (size_t)gyc * WW + gxc);
    unsigned int bm = (mb[(gyc << 5) + (gxc >> 5)] >> (gxc & 31)) & 0xFu;
    if ((gy != gyc) | (gx != gxc)) bm = 16u; // OOB sentinel -> zero vector
    bits[k] = bm;
    lidx[k] = r * TS + c4 * 4;
  }
#pragma unroll
  for (int k = 0; k < 5; ++k) {
    if (k == 4 && tid >= NLOAD - 1024) continue;  // tail: avoid dup writes
    float4 t = v[k];
    unsigned int bm = bits[k];
    if (bm & 1u) t.x = 0.95f;
    if (bm & 2u) t.y = 0.95f;
    if (bm & 4u) t.z = 0.95f;
    if (bm & 8u) t.w = 0.95f;
    if (bm & 16u) { t.x = 0.f; t.y = 0.f; t.z = 0.f; t.w = 0.f; }
    *(float4*)&tile[lidx[k]] = t;
  }
  __syncthreads();

  // ---- compute phase: 4 cols x 4 rows per thread ----
  const int c = tid & 31;          // output cols 4c..4c+3
  const int ty = tid >> 5;         // 0..7: output rows 4ty..4ty+3
  const float* trow = tile + (ty * 4) * TS + c * 4;

  auto hrow = [&](int j, float4& h) {
    const float* p = trow + j * TS;
    float4 A = *(const float4*)(p);       // cols 4c..4c+3
    float4 Bv = *(const float4*)(p + 4);  // cols 4c+4..4c+7
    float2 Cv = *(const float2*)(p + 8);  // cols 4c+8,4c+9
    h.x = G0 * (A.z + Bv.z) + G1 * (A.w + Bv.y) + G2 * Bv.x;
    h.y = G0 * (A.w + Bv.w) + G1 * (Bv.x + Bv.z) + G2 * Bv.y;
    h.z = G0 * (Bv.x + Cv.x) + G1 * (Bv.y + Bv.w) + G2 * Bv.z;
    h.w = G0 * (Bv.y + Cv.y) + G1 * (Bv.z + Cv.x) + G2 * Bv.w;
  };

  float4 h0, h1, h2, h3, h4;
  hrow(0, h0); hrow(1, h1); hrow(2, h2); hrow(3, h3); hrow(4, h4);

  float* op = out + (size_t)bz * (HH * WW) +
              (size_t)(by * 32 + ty * 4) * WW + (bx * 128 + c * 4);
#pragma unroll
  for (int k = 0; k < 4; ++k) {
    float4 s;
    s.x = G0 * (h0.x + h4.x) + G1 * (h1.x + h3.x) + G2 * h2.x;
    s.y = G0 * (h0.y + h4.y) + G1 * (h1.y + h3.y) + G2 * h2.y;
    s.z = G0 * (h0.z + h4.z) + G1 * (h1.z + h3.z) + G2 * h2.z;
    s.w = G0 * (h0.w + h4.w) + G1 * (h1.w + h3.w) + G2 * h2.w;
    s.x = fminf(fmaxf(s.x, 0.f), 1.f);
    s.y = fminf(fmaxf(s.y, 0.f), 1.f);
    s.z = fminf(fmaxf(s.z, 0.f), 1.f);
    s.w = fminf(fmaxf(s.w, 0.f), 1.f);
    *(float4*)op = s;
    op += WW;
    h0 = h1; h1 = h2; h2 = h3; h3 = h4;
    if (k < 3) hrow(k + 5, h4);
  }
}

// ---------------------------------------------------------------------------
extern "C" void kernel_launch(void* const* d_in, const int* in_sizes, int n_in,
                              void* d_out, int out_size, void* d_ws, size_t ws_size,
                              hipStream_t stream) {
  const float* x = (const float*)d_in[0];
  const int* ys = (const int*)d_in[1];
  const int* xs = (const int*)d_in[2];
  const int* rs = (const int*)d_in[3];
  float* out = (float*)d_out;

  unsigned int* mbits = (unsigned int*)d_ws;  // B*H*W/8 = 1 MiB
  hipMemsetAsync(mbits, 0, (size_t)BB * HH * WW / 8, stream);

  dim3 mgrid((NS + 255) / 256, BB);
  snow_mask_kernel<<<mgrid, 256, 0, stream>>>(ys, xs, rs, mbits);

  dim3 grid(WW / 128, HH / 32, BB * CC);
  snow_blur_kernel<<<grid, 256, 0, stream>>>(x, mbits, out);
}